// Round 12
// baseline (54.890 us; speedup 1.0000x reference)
//
#include <hip/hip_runtime.h>
#include <hip/hip_bf16.h>
#include <math.h>

#define BATCH 4
#define CH    64
#define NPOS  4096   // 64*64
#define NGRP  8
#define CPG   8      // CH / NGRP
#define GEPS  1e-5f
#define NSPLIT 8     // K-dim split of attention
#define LOG2E 1.4426950408889634f

typedef __attribute__((ext_vector_type(8))) short bf16x8;   // 8 bf16 = 4 VGPRs
typedef __attribute__((ext_vector_type(4))) float f32x4;

// float -> bf16 bits (round-to-nearest-even)
__device__ __forceinline__ ushort f2bf(float f) {
    union { float f; uint32_t u; } v; v.f = f;
    uint32_t r = v.u + 0x7fffu + ((v.u >> 16) & 1u);
    return (ushort)(r >> 16);
}
__device__ __forceinline__ float bf2f(ushort u) {
    union { uint32_t u; float f; } v; v.u = ((uint32_t)u) << 16; return v.f;
}

// XOR swizzle within a 128B row: logical (row, byteInRow) -> physical byte offset
__device__ __forceinline__ uint32_t swz(uint32_t row, uint32_t byteInRow) {
    return (row << 7) + (byteInRow ^ ((row & 7u) << 4));
}

// 16B ds_read of an MFMA fragment slice
__device__ __forceinline__ bf16x8 ldfrag(const ushort* base, int row, int kbyte) {
    return *(const bf16x8*)((const char*)base + swz(row, kbyte));
}

__device__ __forceinline__ void gload16(const ushort* g, ushort* l) {
    __builtin_amdgcn_global_load_lds((const __attribute__((address_space(1))) void*)g,
                                     (__attribute__((address_space(3))) void*)l,
                                     16, 0, 0);
}

// ---------------------------------------------------------------------------
// Kernel 1: GroupNorm partial sums. Grid 256: block = (bg, slice of 4096).
// ---------------------------------------------------------------------------
__global__ __launch_bounds__(256) void gn_part_kernel(const float* __restrict__ x,
                                                      float2* __restrict__ part) {
    const int blk = blockIdx.x;                      // bg*8 + slice
    const float4* xp4 = (const float4*)(x + (size_t)blk * 4096);
    float s1 = 0.f, s2 = 0.f;
    for (int i = threadIdx.x; i < 1024; i += 256) {
        float4 t = xp4[i];
        s1 += t.x + t.y + t.z + t.w;
        s2 += t.x * t.x + t.y * t.y + t.z * t.z + t.w * t.w;
    }
    __shared__ float sh1[256], sh2[256];
    const int tid = threadIdx.x;
    sh1[tid] = s1; sh2[tid] = s2;
    __syncthreads();
    for (int off = 128; off > 0; off >>= 1) {
        if (tid < off) { sh1[tid] += sh1[tid + off]; sh2[tid] += sh2[tid + off]; }
        __syncthreads();
    }
    if (tid == 0) { float2 r; r.x = sh1[0]; r.y = sh2[0]; part[blk] = r; }
}

// ---------------------------------------------------------------------------
// Kernel 2: fused GN-finish + GroupNorm-apply + ONE of {q,k,v} 1x1 conv.
// Grid 768. Outputs in FRAGMENT-BLOCKED layout (contiguous lane-linear 1KB
// chunks per MFMA fragment):
//   Q_blk[b][qgrp(128 of 32q)][qgi(2)][h(2)][lane(64)][8]
//   K_blk[b][kt(64)][nt(4)][h(2)][lane(64)][8]
//   V_blk[b][kt(64)][ct(4)][h(2)][lane(64)][8]
// q folds bias and 0.125*log2e (exp2-domain softmax).
// ---------------------------------------------------------------------------
__global__ __launch_bounds__(256) void qkv_mfma_kernel(
    const float* __restrict__ x, const float2* __restrict__ part,
    const float* __restrict__ gamma, const float* __restrict__ beta,
    const float* __restrict__ Wq, const float* __restrict__ bq,
    const float* __restrict__ Wk, const float* __restrict__ bk,
    const float* __restrict__ Wv, const float* __restrict__ bv,
    ushort* __restrict__ qg, ushort* __restrict__ kg, ushort* __restrict__ vg)
{
    __shared__ ushort xn[64 * 64];     // [n][c] swizzled bf16
    __shared__ ushort Wl[64 * 64];     // W [o][c] swizzled bf16
    __shared__ ushort ob[64 * 64];     // output bounce
    __shared__ float st[16];           // 8 groups * {mean, rstd} for this b

    const int tid = threadIdx.x;
    const int w = tid >> 6, lane = tid & 63, g = lane >> 4, q16 = lane & 15;
    const int m = blockIdx.x >> 8;               // 0=q 1=k 2=v
    const int bidx = blockIdx.x & 255;
    const int b = bidx >> 6, n0 = (bidx & 63) << 6;

    const float* W = (m == 0) ? Wq : (m == 1) ? Wk : Wv;

    {
        const int row = tid >> 2, cb = (tid & 3) << 4;
#pragma unroll
        for (int j = 0; j < 4; ++j) {
            float4 v = *(const float4*)(W + row * 64 + cb + j * 4);
            ushort4 h; h.x = f2bf(v.x); h.y = f2bf(v.y); h.z = f2bf(v.z); h.w = f2bf(v.w);
            *(ushort4*)((char*)Wl + swz(row, (cb + j * 4) * 2)) = h;
        }
    }
    if (tid < 64) {
        float2 p = part[b * 64 + tid];
        float s1 = p.x, s2 = p.y;
        s1 += __shfl_xor(s1, 1); s2 += __shfl_xor(s2, 1);
        s1 += __shfl_xor(s1, 2); s2 += __shfl_xor(s2, 2);
        s1 += __shfl_xor(s1, 4); s2 += __shfl_xor(s2, 4);
        if ((tid & 7) == 0) {
            const float inv = 1.0f / (float)(CPG * NPOS);
            float mean = s1 * inv;
            float var  = s2 * inv - mean * mean;
            st[(tid >> 3) * 2]     = mean;
            st[(tid >> 3) * 2 + 1] = rsqrtf(var + GEPS);
        }
    }
    __syncthreads();

    {
        const int c = tid >> 2, nb = (tid & 3) << 4;
        const float mean = st[(c >> 3) * 2];
        const float rstd = st[(c >> 3) * 2 + 1];
        const float gmm = gamma[c] * rstd;
        const float btt = beta[c] - mean * gmm;
        const float* xp = x + (((size_t)(b * CH + c)) << 12) + n0 + nb;
#pragma unroll
        for (int j = 0; j < 4; ++j) {
            float4 v = *(const float4*)(xp + j * 4);
            float vv[4] = {v.x, v.y, v.z, v.w};
#pragma unroll
            for (int e = 0; e < 4; ++e) {
                int n = nb + j * 4 + e;
                *(ushort*)((char*)xn + swz(n, c * 2)) = f2bf(vv[e] * gmm + btt);
            }
        }
    }
    __syncthreads();

    if (m < 2) {
        // ---- q/k: D[n][o] = xn[n][c] * W^T ----
        const float* bias = m ? bk : bq;
        const float scl = m ? 1.0f : 0.125f * LOG2E;   // q in exp2 domain
        bf16x8 ax0 = ldfrag(xn, (w << 4) + q16, (g << 4));
        bf16x8 ax1 = ldfrag(xn, (w << 4) + q16, 64 + (g << 4));
#pragma unroll
        for (int ot = 0; ot < 4; ++ot) {
            f32x4 acc = {0.f, 0.f, 0.f, 0.f};
            bf16x8 b0 = ldfrag(Wl, (ot << 4) + q16, (g << 4));
            bf16x8 b1 = ldfrag(Wl, (ot << 4) + q16, 64 + (g << 4));
            acc = __builtin_amdgcn_mfma_f32_16x16x32_bf16(ax0, b0, acc, 0, 0, 0);
            acc = __builtin_amdgcn_mfma_f32_16x16x32_bf16(ax1, b1, acc, 0, 0, 0);
            float bs = bias[(ot << 4) + q16];
#pragma unroll
            for (int r = 0; r < 4; ++r)
                *(ushort*)((char*)ob + swz((w << 4) + (g << 2) + r, ((ot << 4) + q16) << 1)) =
                    f2bf((acc[r] + bs) * scl);
        }
        __syncthreads();
        // ---- blocked store: ob[n][c] -> fragment chunks ----
        ushort* dst = (m ? kg : qg) + (((size_t)b) << 18);
#pragma unroll
        for (int i = 0; i < 2; ++i) {
            const int G = tid + (i << 8);            // 0..511
            const int lane_ = G & 63;
            const int h = (G >> 6) & 1;
            const int colb = (h << 5) + ((lane_ >> 4) << 3);   // ushorts
            if (m == 0) {
                const int qgi = (G >> 7) & 1;
                const int qgl = G >> 8;              // 0..1 (two 32-q groups)
                const int row = (qgl << 5) + (qgi << 4) + (lane_ & 15);
                int4 d = *(const int4*)((char*)ob + swz(row, colb << 1));
                *(int4*)(dst + (((size_t)(n0 >> 5) + qgl) << 11)
                             + ((size_t)((((qgi << 1) + h) << 6) + lane_) << 3)) = d;
            } else {
                const int nt = G >> 7;               // 0..3
                const int row = (nt << 4) + (lane_ & 15);
                int4 d = *(const int4*)((char*)ob + swz(row, colb << 1));
                *(int4*)(dst + ((size_t)(n0 >> 6) << 12)
                             + ((size_t)((((nt << 1) + h) << 6) + lane_) << 3)) = d;
            }
        }
    } else {
        // ---- v: D[o][n] = Wv * xn^T ----
        bf16x8 aw0 = ldfrag(Wl, (w << 4) + q16, (g << 4));
        bf16x8 aw1 = ldfrag(Wl, (w << 4) + q16, 64 + (g << 4));
#pragma unroll
        for (int nt = 0; nt < 4; ++nt) {
            f32x4 acc = {0.f, 0.f, 0.f, 0.f};
            bf16x8 b0 = ldfrag(xn, (nt << 4) + q16, (g << 4));
            bf16x8 b1 = ldfrag(xn, (nt << 4) + q16, 64 + (g << 4));
            acc = __builtin_amdgcn_mfma_f32_16x16x32_bf16(aw0, b0, acc, 0, 0, 0);
            acc = __builtin_amdgcn_mfma_f32_16x16x32_bf16(aw1, b1, acc, 0, 0, 0);
#pragma unroll
            for (int r = 0; r < 4; ++r) {
                float bs = bv[(w << 4) + (g << 2) + r];
                *(ushort*)((char*)ob + swz((w << 4) + (g << 2) + r, ((nt << 4) + q16) << 1)) =
                    f2bf(acc[r] + bs);
            }
        }
        __syncthreads();
        // ---- blocked store: ob[c][n_local] -> fragment chunks ----
        ushort* dst = vg + (((size_t)b) << 18) + ((size_t)(n0 >> 6) << 12);
#pragma unroll
        for (int i = 0; i < 2; ++i) {
            const int G = tid + (i << 8);            // 0..511
            const int lane_ = G & 63;
            const int h = (G >> 6) & 1;
            const int ct = G >> 7;                   // 0..3
            const int row = (ct << 4) + (lane_ & 15);        // channel
            const int colb = (h << 5) + ((lane_ >> 4) << 3); // key-local
            int4 d = *(const int4*)((char*)ob + swz(row, colb << 1));
            *(int4*)(dst + ((size_t)((((ct << 1) + h) << 6) + lane_) << 3)) = d;
        }
    }
}

// ---------------------------------------------------------------------------
// Kernel 3: attention, softmax-free (P = 2^s), K-split x8, 32 q per wave.
// NEW: K/V tiles staged into LDS ONCE PER BLOCK via global_load_lds (the
// fragment-blocked layout makes each 1KB fragment exactly one lane-linear
// gload16). Removes the 4x intra-block L2 fragment redundancy (512->128 MB).
// Double-buffered tiles; ONE barrier per 64-key tile (its vmcnt drain is the
// prefetch fence). Grid 1024 = b(4) x qblk(32 of 128q) x ks(8); 4 waves.
// LDS 48KB -> 3 blocks/CU.
// ---------------------------------------------------------------------------
#define STAGE(KT, NB)                                                          \
  do {                                                                         \
    _Pragma("unroll") for (int i = 0; i < 2; ++i) {                            \
        const int ch = (w << 1) + i;                                           \
        gload16(kp + (((size_t)(KT)) << 12) + (ch << 9) + (lane << 3),         \
                &Kt[NB][(ch << 9) + (lane << 3)]);                             \
        gload16(vp + (((size_t)(KT)) << 12) + (ch << 9) + (lane << 3),         \
                &Vt[NB][(ch << 9) + (lane << 3)]);                             \
    }                                                                          \
  } while (0)

__global__ __launch_bounds__(256) void attn_mfma_kernel(
    const ushort* __restrict__ qg, const ushort* __restrict__ kg,
    const ushort* __restrict__ vg,
    ushort* __restrict__ opart, float* __restrict__ lpart)
{
    __shared__ ushort Kt[2][4096];      // 8KB per buf: 8 fragments x 1KB
    __shared__ ushort Vt[2][4096];
    __shared__ ushort Ps[4][32 * 64];   // per-wave P arena [q][key], swz rows

    const int tid = threadIdx.x;
    const int w = tid >> 6, lane = tid & 63, lg = lane >> 4, q16 = lane & 15;
    // bijective XCD swizzle: 1024 wg = 8 xcd chunks of 128
    const int logical = ((blockIdx.x & 7) << 7) + (blockIdx.x >> 3);
    const int ks = logical & 7;
    const int qb = (logical >> 3) & 31;       // 32 q-blocks of 128
    const int b  = logical >> 8;
    const int q0 = (qb << 7) + (w << 5);      // wave's 32 q
    // blocked bases
    const ushort* qp = qg + (((size_t)b) << 18) + ((size_t)((qb << 2) + w) << 11);
    const ushort* kp = kg + (((size_t)b) << 18) + ((size_t)ks << 15);
    const ushort* vp = vg + (((size_t)b) << 18) + ((size_t)ks << 15);
    ushort* Pw = Ps[w];

    // stage tile 0 into buffer 0 (4 gload16 per wave, 16 per block)
    STAGE(0, 0);

    // hoist Q B-fragments (32 q x 64 c): contiguous lane-linear chunks
    bf16x8 aq[2][2];
#pragma unroll
    for (int qgi = 0; qgi < 2; ++qgi)
#pragma unroll
        for (int h = 0; h < 2; ++h)
            aq[qgi][h] = *(const bf16x8*)(qp + ((size_t)((((qgi << 1) + h) << 6) + lane) << 3));

    float l_[2] = {0.f, 0.f};
    f32x4 o_[4][2];                       // [ct][qgi]
#pragma unroll
    for (int ct = 0; ct < 4; ++ct)
#pragma unroll
        for (int qgi = 0; qgi < 2; ++qgi) o_[ct][qgi] = (f32x4){0.f, 0.f, 0.f, 0.f};

    __syncthreads();                      // tile 0 resident (vmcnt drained)

    int buf = 0;
#pragma unroll 1
    for (int kt = 0; kt < 8; ++kt) {
        if (kt < 7) STAGE(kt + 1, buf ^ 1);   // prefetch next tile

        // ---- S = K.Q^T from LDS K fragments ----
        f32x4 s_[4][2];
#pragma unroll
        for (int nt = 0; nt < 4; ++nt) {
            bf16x8 k0 = *(const bf16x8*)(&Kt[buf][((nt << 1) << 9) + (lane << 3)]);
            bf16x8 k1 = *(const bf16x8*)(&Kt[buf][(((nt << 1) + 1) << 9) + (lane << 3)]);
#pragma unroll
            for (int qgi = 0; qgi < 2; ++qgi) {
                f32x4 z = {0.f, 0.f, 0.f, 0.f};
                z = __builtin_amdgcn_mfma_f32_16x16x32_bf16(k0, aq[qgi][0], z, 0, 0, 0);
                z = __builtin_amdgcn_mfma_f32_16x16x32_bf16(k1, aq[qgi][1], z, 0, 0, 0);
                s_[nt][qgi] = z;
            }
        }
        // ---- P = 2^s (no max needed; scores bounded), pack to LDS ----
#pragma unroll
        for (int qgi = 0; qgi < 2; ++qgi) {
#pragma unroll
            for (int nt = 0; nt < 4; ++nt) {
                float p0 = exp2f(s_[nt][qgi][0]);
                float p1 = exp2f(s_[nt][qgi][1]);
                float p2 = exp2f(s_[nt][qgi][2]);
                float p3 = exp2f(s_[nt][qgi][3]);
                l_[qgi] += (p0 + p1) + (p2 + p3);
                float2 t01; t01.x = p0; t01.y = p1;
                float2 t23; t23.x = p2; t23.y = p3;
                __hip_bfloat162 b01 = __float22bfloat162_rn(t01);
                __hip_bfloat162 b23 = __float22bfloat162_rn(t23);
                uint2 pk; pk.x = *(uint32_t*)&b01; pk.y = *(uint32_t*)&b23;
                *(uint2*)((char*)Pw + swz((qgi << 4) + q16, (nt << 5) + (lg << 3))) = pk;
            }
        }
        asm volatile("" ::: "memory");    // keep P writes before P reads
        // ---- O^T += V^T . P^T  (V fragments from LDS) ----
        bf16x8 pb[2][2];
#pragma unroll
        for (int qgi = 0; qgi < 2; ++qgi) {
            pb[qgi][0] = ldfrag(Pw, (qgi << 4) + q16, (lg << 4));
            pb[qgi][1] = ldfrag(Pw, (qgi << 4) + q16, 64 + (lg << 4));
        }
#pragma unroll
        for (int ct = 0; ct < 4; ++ct) {
            bf16x8 v0 = *(const bf16x8*)(&Vt[buf][((ct << 1) << 9) + (lane << 3)]);
            bf16x8 v1 = *(const bf16x8*)(&Vt[buf][(((ct << 1) + 1) << 9) + (lane << 3)]);
#pragma unroll
            for (int qgi = 0; qgi < 2; ++qgi) {
                f32x4 o = o_[ct][qgi];
                o = __builtin_amdgcn_mfma_f32_16x16x32_bf16(v0, pb[qgi][0], o, 0, 0, 0);
                o = __builtin_amdgcn_mfma_f32_16x16x32_bf16(v1, pb[qgi][1], o, 0, 0, 0);
                o_[ct][qgi] = o;
            }
        }
        __syncthreads();                  // prefetch landed + buf reads done
        buf ^= 1;
    }

    // deferred l reduction (once, not per tile)
#pragma unroll
    for (int qgi = 0; qgi < 2; ++qgi) {
        l_[qgi] += __shfl_xor(l_[qgi], 16);
        l_[qgi] += __shfl_xor(l_[qgi], 32);
    }

    // ---- store partial O~^T[c][n] (bf16) + l (f32) ----
    const size_t bs = (size_t)(b * NSPLIT + ks);
#pragma unroll
    for (int qgi = 0; qgi < 2; ++qgi) {
        const int n = q0 + (qgi << 4) + q16;
        ushort* ob = opart + ((bs * 64) << 12) + n;
#pragma unroll
        for (int ct = 0; ct < 4; ++ct)
#pragma unroll
            for (int r = 0; r < 4; ++r)
                ob[((size_t)((ct << 4) + (lg << 2) + r)) << 12] = f2bf(o_[ct][qgi][r]);
    }
    if (lg == 0) {
#pragma unroll
        for (int qgi = 0; qgi < 2; ++qgi) {
            const int n = q0 + (qgi << 4) + q16;
            lpart[bs * 4096 + n] = l_[qgi];
        }
    }
}

// ---------------------------------------------------------------------------
// Kernel 4: split-combine (plain sums) + output projection + bias + residual.
// Grid 256 = b(4) x ntile(64); 256 thr = 4 waves.
// ---------------------------------------------------------------------------
__global__ __launch_bounds__(256) void combine_kernel(
    const ushort* __restrict__ opart, const float* __restrict__ lpart,
    const float* __restrict__ x, const float* __restrict__ Wp,
    const float* __restrict__ bp, float* __restrict__ out)
{
    __shared__ ushort Obf[64 * 64];    // combined O [n][c] bf16 swizzled
    __shared__ ushort Wps[64 * 64];    // Wp [oc][c] bf16 swizzled
    __shared__ float as_[64];          // 1/sum_l per n_local

    const int tid = threadIdx.x;
    const int w = tid >> 6, lane = tid & 63, g = lane >> 4, q16 = lane & 15;
    const int b = blockIdx.x >> 6, n0 = (blockIdx.x & 63) << 6;

    {
        const int row = tid >> 2, cb = (tid & 3) << 4;
#pragma unroll
        for (int j = 0; j < 4; ++j) {
            float4 v = *(const float4*)(Wp + row * 64 + cb + j * 4);
            ushort4 h; h.x = f2bf(v.x); h.y = f2bf(v.y); h.z = f2bf(v.z); h.w = f2bf(v.w);
            *(ushort4*)((char*)Wps + swz(row, (cb + j * 4) * 2)) = h;
        }
    }
    if (tid < 64) {
        const int n = n0 + tid;
        float d = 0.f;
#pragma unroll
        for (int s = 0; s < NSPLIT; ++s)
            d += lpart[(size_t)(b * NSPLIT + s) * 4096 + n];
        as_[tid] = 1.0f / d;
    }
    __syncthreads();

    {
        const int c = tid >> 2, nb = (tid & 3) << 4;
        const ushort* base = opart + ((((size_t)(b * NSPLIT)) * 64 + c) << 12) + n0 + nb;
        const size_t sstride = (size_t)64 << 12;   // split stride in ushorts
        float acc[16];
#pragma unroll
        for (int e = 0; e < 16; ++e) acc[e] = 0.f;
#pragma unroll
        for (int s = 0; s < NSPLIT; ++s) {
            const ushort* p = base + s * sstride;
            uint4 d0 = *(const uint4*)(p);
            uint4 d1 = *(const uint4*)(p + 8);
            const uint uw[8] = {d0.x, d0.y, d0.z, d0.w, d1.x, d1.y, d1.z, d1.w};
#pragma unroll
            for (int j = 0; j < 8; ++j) {
                acc[2 * j]     += bf2f((ushort)(uw[j] & 0xffffu));
                acc[2 * j + 1] += bf2f((ushort)(uw[j] >> 16));
            }
        }
#pragma unroll
        for (int e = 0; e < 16; ++e) {
            int nl = nb + e;
            *(ushort*)((char*)Obf + swz(nl, c << 1)) = f2bf(acc[e] * as_[nl]);
        }
    }
    __syncthreads();

    {
        bf16x8 aw0 = ldfrag(Wps, (w << 4) + q16, (g << 4));
        bf16x8 aw1 = ldfrag(Wps, (w << 4) + q16, 64 + (g << 4));
        float bpv[4];
#pragma unroll
        for (int r = 0; r < 4; ++r) bpv[r] = bp[(w << 4) + (g << 2) + r];
#pragma unroll
        for (int qt = 0; qt < 4; ++qt) {
            f32x4 d = {0.f, 0.f, 0.f, 0.f};
            bf16x8 b0 = ldfrag(Obf, (qt << 4) + q16, (g << 4));
            bf16x8 b1 = ldfrag(Obf, (qt << 4) + q16, 64 + (g << 4));
            d = __builtin_amdgcn_mfma_f32_16x16x32_bf16(aw0, b0, d, 0, 0, 0);
            d = __builtin_amdgcn_mfma_f32_16x16x32_bf16(aw1, b1, d, 0, 0, 0);
#pragma unroll
            for (int r = 0; r < 4; ++r) {
                int oc = (w << 4) + (g << 2) + r;
                size_t addr = (((size_t)(b * CH + oc)) << 12) + n0 + (qt << 4) + q16;
                out[addr] = d[r] + bpv[r] + x[addr];
            }
        }
    }
}

// ---------------------------------------------------------------------------
extern "C" void kernel_launch(void* const* d_in, const int* in_sizes, int n_in,
                              void* d_out, int out_size, void* d_ws, size_t ws_size,
                              hipStream_t stream) {
    const float* x     = (const float*)d_in[0];
    const float* gamma = (const float*)d_in[1];
    const float* beta  = (const float*)d_in[2];
    const float* Wq    = (const float*)d_in[3];
    const float* bq    = (const float*)d_in[4];
    const float* Wk    = (const float*)d_in[5];
    const float* bk    = (const float*)d_in[6];
    const float* Wv    = (const float*)d_in[7];
    const float* bv    = (const float*)d_in[8];
    const float* Wp    = (const float*)d_in[9];
    const float* bp    = (const float*)d_in[10];
    float* out = (float*)d_out;

    float2* part = (float2*)d_ws;                      // 256 float2 = 2KB
    ushort* q_t = (ushort*)((char*)d_ws + 4096);       // blocked Q, 2MB
    ushort* k_t = q_t + (size_t)BATCH * NPOS * CH;     // blocked K, 2MB
    ushort* v_t = k_t + (size_t)BATCH * NPOS * CH;     // blocked V, 2MB
    ushort* opart = (ushort*)((char*)d_ws + 4096 + (size_t)3 * BATCH * NPOS * CH * 2);
    float* lpart = (float*)((char*)opart + (size_t)BATCH * NSPLIT * CH * NPOS * 2);

    hipLaunchKernelGGL(gn_part_kernel, dim3(256), dim3(256), 0, stream, x, part);
    hipLaunchKernelGGL(qkv_mfma_kernel, dim3(768), dim3(256), 0, stream,
                       x, part, gamma, beta, Wq, bq, Wk, bk, Wv, bv, q_t, k_t, v_t);
    hipLaunchKernelGGL(attn_mfma_kernel, dim3(1024), dim3(256), 0, stream,
                       q_t, k_t, v_t, opart, lpart);
    hipLaunchKernelGGL(combine_kernel, dim3(BATCH * 64), dim3(256), 0, stream,
                       opart, lpart, x, Wp, bp, out);
}

// Round 13
// 51.433 us; speedup vs baseline: 1.0672x; 1.0672x over previous
//
#include <hip/hip_runtime.h>
#include <hip/hip_bf16.h>
#include <math.h>

#define BATCH 4
#define CH    64
#define NPOS  4096   // 64*64
#define NGRP  8
#define CPG   8      // CH / NGRP
#define GEPS  1e-5f
#define NSPLIT 8     // K-dim split of attention
#define LOG2E 1.4426950408889634f

typedef __attribute__((ext_vector_type(8))) short bf16x8;   // 8 bf16 = 4 VGPRs
typedef __attribute__((ext_vector_type(4))) float f32x4;

// float -> bf16 bits (round-to-nearest-even)
__device__ __forceinline__ ushort f2bf(float f) {
    union { float f; uint32_t u; } v; v.f = f;
    uint32_t r = v.u + 0x7fffu + ((v.u >> 16) & 1u);
    return (ushort)(r >> 16);
}
__device__ __forceinline__ float bf2f(ushort u) {
    union { uint32_t u; float f; } v; v.u = ((uint32_t)u) << 16; return v.f;
}

// XOR swizzle within a 128B row: logical (row, byteInRow) -> physical byte offset
__device__ __forceinline__ uint32_t swz(uint32_t row, uint32_t byteInRow) {
    return (row << 7) + (byteInRow ^ ((row & 7u) << 4));
}

// 16B ds_read of an MFMA fragment slice
__device__ __forceinline__ bf16x8 ldfrag(const ushort* base, int row, int kbyte) {
    return *(const bf16x8*)((const char*)base + swz(row, kbyte));
}

// ---------------------------------------------------------------------------
// Kernel 1: GroupNorm partial sums. Grid 256: block = (bg, slice of 4096).
// ---------------------------------------------------------------------------
__global__ __launch_bounds__(256) void gn_part_kernel(const float* __restrict__ x,
                                                      float2* __restrict__ part) {
    const int blk = blockIdx.x;                      // bg*8 + slice
    const float4* xp4 = (const float4*)(x + (size_t)blk * 4096);
    float s1 = 0.f, s2 = 0.f;
    for (int i = threadIdx.x; i < 1024; i += 256) {
        float4 t = xp4[i];
        s1 += t.x + t.y + t.z + t.w;
        s2 += t.x * t.x + t.y * t.y + t.z * t.z + t.w * t.w;
    }
    __shared__ float sh1[256], sh2[256];
    const int tid = threadIdx.x;
    sh1[tid] = s1; sh2[tid] = s2;
    __syncthreads();
    for (int off = 128; off > 0; off >>= 1) {
        if (tid < off) { sh1[tid] += sh1[tid + off]; sh2[tid] += sh2[tid + off]; }
        __syncthreads();
    }
    if (tid == 0) { float2 r; r.x = sh1[0]; r.y = sh2[0]; part[blk] = r; }
}

// ---------------------------------------------------------------------------
// Kernel 2: fused GN-finish + GroupNorm-apply + ONE of {q,k,v} 1x1 conv.
// Grid 768. Outputs in FRAGMENT-BLOCKED layout (contiguous lane-linear 1KB
// chunks per MFMA fragment):
//   Q_blk[b][qgrp(128 of 32q)][qgi(2)][h(2)][lane(64)][8]
//   K_blk[b][kt(64)][nt(4)][h(2)][lane(64)][8]
//   V_blk[b][kt(64)][ct(4)][h(2)][lane(64)][8]
// q folds bias and 0.125*log2e (exp2-domain softmax).
// ---------------------------------------------------------------------------
__global__ __launch_bounds__(256) void qkv_mfma_kernel(
    const float* __restrict__ x, const float2* __restrict__ part,
    const float* __restrict__ gamma, const float* __restrict__ beta,
    const float* __restrict__ Wq, const float* __restrict__ bq,
    const float* __restrict__ Wk, const float* __restrict__ bk,
    const float* __restrict__ Wv, const float* __restrict__ bv,
    ushort* __restrict__ qg, ushort* __restrict__ kg, ushort* __restrict__ vg)
{
    __shared__ ushort xn[64 * 64];     // [n][c] swizzled bf16
    __shared__ ushort Wl[64 * 64];     // W [o][c] swizzled bf16
    __shared__ ushort ob[64 * 64];     // output bounce
    __shared__ float st[16];           // 8 groups * {mean, rstd} for this b

    const int tid = threadIdx.x;
    const int w = tid >> 6, lane = tid & 63, g = lane >> 4, q16 = lane & 15;
    const int m = blockIdx.x >> 8;               // 0=q 1=k 2=v
    const int bidx = blockIdx.x & 255;
    const int b = bidx >> 6, n0 = (bidx & 63) << 6;

    const float* W = (m == 0) ? Wq : (m == 1) ? Wk : Wv;

    {
        const int row = tid >> 2, cb = (tid & 3) << 4;
#pragma unroll
        for (int j = 0; j < 4; ++j) {
            float4 v = *(const float4*)(W + row * 64 + cb + j * 4);
            ushort4 h; h.x = f2bf(v.x); h.y = f2bf(v.y); h.z = f2bf(v.z); h.w = f2bf(v.w);
            *(ushort4*)((char*)Wl + swz(row, (cb + j * 4) * 2)) = h;
        }
    }
    if (tid < 64) {
        float2 p = part[b * 64 + tid];
        float s1 = p.x, s2 = p.y;
        s1 += __shfl_xor(s1, 1); s2 += __shfl_xor(s2, 1);
        s1 += __shfl_xor(s1, 2); s2 += __shfl_xor(s2, 2);
        s1 += __shfl_xor(s1, 4); s2 += __shfl_xor(s2, 4);
        if ((tid & 7) == 0) {
            const float inv = 1.0f / (float)(CPG * NPOS);
            float mean = s1 * inv;
            float var  = s2 * inv - mean * mean;
            st[(tid >> 3) * 2]     = mean;
            st[(tid >> 3) * 2 + 1] = rsqrtf(var + GEPS);
        }
    }
    __syncthreads();

    {
        const int c = tid >> 2, nb = (tid & 3) << 4;
        const float mean = st[(c >> 3) * 2];
        const float rstd = st[(c >> 3) * 2 + 1];
        const float gmm = gamma[c] * rstd;
        const float btt = beta[c] - mean * gmm;
        const float* xp = x + (((size_t)(b * CH + c)) << 12) + n0 + nb;
#pragma unroll
        for (int j = 0; j < 4; ++j) {
            float4 v = *(const float4*)(xp + j * 4);
            float vv[4] = {v.x, v.y, v.z, v.w};
#pragma unroll
            for (int e = 0; e < 4; ++e) {
                int n = nb + j * 4 + e;
                *(ushort*)((char*)xn + swz(n, c * 2)) = f2bf(vv[e] * gmm + btt);
            }
        }
    }
    __syncthreads();

    if (m < 2) {
        // ---- q/k: D[n][o] = xn[n][c] * W^T ----
        const float* bias = m ? bk : bq;
        const float scl = m ? 1.0f : 0.125f * LOG2E;   // q in exp2 domain
        bf16x8 ax0 = ldfrag(xn, (w << 4) + q16, (g << 4));
        bf16x8 ax1 = ldfrag(xn, (w << 4) + q16, 64 + (g << 4));
#pragma unroll
        for (int ot = 0; ot < 4; ++ot) {
            f32x4 acc = {0.f, 0.f, 0.f, 0.f};
            bf16x8 b0 = ldfrag(Wl, (ot << 4) + q16, (g << 4));
            bf16x8 b1 = ldfrag(Wl, (ot << 4) + q16, 64 + (g << 4));
            acc = __builtin_amdgcn_mfma_f32_16x16x32_bf16(ax0, b0, acc, 0, 0, 0);
            acc = __builtin_amdgcn_mfma_f32_16x16x32_bf16(ax1, b1, acc, 0, 0, 0);
            float bs = bias[(ot << 4) + q16];
#pragma unroll
            for (int r = 0; r < 4; ++r)
                *(ushort*)((char*)ob + swz((w << 4) + (g << 2) + r, ((ot << 4) + q16) << 1)) =
                    f2bf((acc[r] + bs) * scl);
        }
        __syncthreads();
        // ---- blocked store: ob[n][c] -> fragment chunks ----
        ushort* dst = (m ? kg : qg) + (((size_t)b) << 18);
#pragma unroll
        for (int i = 0; i < 2; ++i) {
            const int G = tid + (i << 8);            // 0..511
            const int lane_ = G & 63;
            const int h = (G >> 6) & 1;
            const int colb = (h << 5) + ((lane_ >> 4) << 3);   // ushorts
            if (m == 0) {
                const int qgi = (G >> 7) & 1;
                const int qgl = G >> 8;              // 0..1 (two 32-q groups)
                const int row = (qgl << 5) + (qgi << 4) + (lane_ & 15);
                int4 d = *(const int4*)((char*)ob + swz(row, colb << 1));
                *(int4*)(dst + (((size_t)(n0 >> 5) + qgl) << 11)
                             + ((size_t)((((qgi << 1) + h) << 6) + lane_) << 3)) = d;
            } else {
                const int nt = G >> 7;               // 0..3
                const int row = (nt << 4) + (lane_ & 15);
                int4 d = *(const int4*)((char*)ob + swz(row, colb << 1));
                *(int4*)(dst + ((size_t)(n0 >> 6) << 12)
                             + ((size_t)((((nt << 1) + h) << 6) + lane_) << 3)) = d;
            }
        }
    } else {
        // ---- v: D[o][n] = Wv * xn^T ----
        bf16x8 aw0 = ldfrag(Wl, (w << 4) + q16, (g << 4));
        bf16x8 aw1 = ldfrag(Wl, (w << 4) + q16, 64 + (g << 4));
#pragma unroll
        for (int nt = 0; nt < 4; ++nt) {
            f32x4 acc = {0.f, 0.f, 0.f, 0.f};
            bf16x8 b0 = ldfrag(xn, (nt << 4) + q16, (g << 4));
            bf16x8 b1 = ldfrag(xn, (nt << 4) + q16, 64 + (g << 4));
            acc = __builtin_amdgcn_mfma_f32_16x16x32_bf16(aw0, b0, acc, 0, 0, 0);
            acc = __builtin_amdgcn_mfma_f32_16x16x32_bf16(aw1, b1, acc, 0, 0, 0);
#pragma unroll
            for (int r = 0; r < 4; ++r) {
                float bs = bv[(w << 4) + (g << 2) + r];
                *(ushort*)((char*)ob + swz((w << 4) + (g << 2) + r, ((nt << 4) + q16) << 1)) =
                    f2bf(acc[r] + bs);
            }
        }
        __syncthreads();
        // ---- blocked store: ob[c][n_local] -> fragment chunks ----
        ushort* dst = vg + (((size_t)b) << 18) + ((size_t)(n0 >> 6) << 12);
#pragma unroll
        for (int i = 0; i < 2; ++i) {
            const int G = tid + (i << 8);            // 0..511
            const int lane_ = G & 63;
            const int h = (G >> 6) & 1;
            const int ct = G >> 7;                   // 0..3
            const int row = (ct << 4) + (lane_ & 15);        // channel
            const int colb = (h << 5) + ((lane_ >> 4) << 3); // key-local
            int4 d = *(const int4*)((char*)ob + swz(row, colb << 1));
            *(int4*)(dst + ((size_t)((((ct << 1) + h) << 6) + lane_) << 3)) = d;
        }
    }
}

// ---------------------------------------------------------------------------
// Kernel 3: attention, softmax-free (P = 2^s), K-split x8 — r11 structure
// (proven best, 52.9us total): 1024 blocks x 4 waves; 32 q/wave; blocked-
// layout direct-L2 fragment loads; named K dbuf kfA/kfB; deferred l reduce.
// ---------------------------------------------------------------------------
#define LOADK(KF, KT)                                                          \
    _Pragma("unroll") for (int nt = 0; nt < 4; ++nt)                           \
    _Pragma("unroll") for (int h = 0; h < 2; ++h)                              \
        KF[nt][h] = *(const bf16x8*)(kp + (((size_t)(KT)) << 12) +             \
                     ((size_t)((((nt << 1) + h) << 6) + lane) << 3));

#define STEP(KF, KFN, KT, PREF)                                                \
  do {                                                                         \
    bf16x8 vf[4][2];                                                           \
    _Pragma("unroll") for (int ct = 0; ct < 4; ++ct)                           \
    _Pragma("unroll") for (int h = 0; h < 2; ++h)                              \
        vf[ct][h] = *(const bf16x8*)(vp + (((size_t)(KT)) << 12) +             \
                     ((size_t)((((ct << 1) + h) << 6) + lane) << 3));          \
    if (PREF) { LOADK(KFN, (KT) + 1); }                                        \
    f32x4 s_[4][2];                                                            \
    _Pragma("unroll") for (int nt = 0; nt < 4; ++nt)                           \
    _Pragma("unroll") for (int qgi = 0; qgi < 2; ++qgi) {                      \
        f32x4 z = {0.f, 0.f, 0.f, 0.f};                                        \
        z = __builtin_amdgcn_mfma_f32_16x16x32_bf16(KF[nt][0], aq[qgi][0], z, 0, 0, 0); \
        z = __builtin_amdgcn_mfma_f32_16x16x32_bf16(KF[nt][1], aq[qgi][1], z, 0, 0, 0); \
        s_[nt][qgi] = z;                                                       \
    }                                                                          \
    _Pragma("unroll") for (int qgi = 0; qgi < 2; ++qgi) {                      \
        _Pragma("unroll") for (int nt = 0; nt < 4; ++nt) {                     \
            float p0 = exp2f(s_[nt][qgi][0]);                                  \
            float p1 = exp2f(s_[nt][qgi][1]);                                  \
            float p2 = exp2f(s_[nt][qgi][2]);                                  \
            float p3 = exp2f(s_[nt][qgi][3]);                                  \
            l_[qgi] += (p0 + p1) + (p2 + p3);                                  \
            float2 t01; t01.x = p0; t01.y = p1;                                \
            float2 t23; t23.x = p2; t23.y = p3;                                \
            __hip_bfloat162 b01 = __float22bfloat162_rn(t01);                  \
            __hip_bfloat162 b23 = __float22bfloat162_rn(t23);                  \
            uint2 pk; pk.x = *(uint32_t*)&b01; pk.y = *(uint32_t*)&b23;        \
            *(uint2*)((char*)Pw + swz((qgi << 4) + q16, (nt << 5) + (lg << 3))) = pk; \
        }                                                                      \
    }                                                                          \
    asm volatile("" ::: "memory");                                             \
    bf16x8 pb[2][2];                                                           \
    _Pragma("unroll") for (int qgi = 0; qgi < 2; ++qgi) {                      \
        pb[qgi][0] = ldfrag(Pw, (qgi << 4) + q16, (lg << 4));                  \
        pb[qgi][1] = ldfrag(Pw, (qgi << 4) + q16, 64 + (lg << 4));             \
    }                                                                          \
    _Pragma("unroll") for (int ct = 0; ct < 4; ++ct)                           \
    _Pragma("unroll") for (int qgi = 0; qgi < 2; ++qgi) {                      \
        f32x4 o = o_[ct][qgi];                                                 \
        o = __builtin_amdgcn_mfma_f32_16x16x32_bf16(vf[ct][0], pb[qgi][0], o, 0, 0, 0); \
        o = __builtin_amdgcn_mfma_f32_16x16x32_bf16(vf[ct][1], pb[qgi][1], o, 0, 0, 0); \
        o_[ct][qgi] = o;                                                       \
    }                                                                          \
  } while (0)

__global__ __launch_bounds__(256) void attn_mfma_kernel(
    const ushort* __restrict__ qg, const ushort* __restrict__ kg,
    const ushort* __restrict__ vg,
    ushort* __restrict__ opart, float* __restrict__ lpart)
{
    __shared__ ushort Ps[4][32 * 64];   // per-wave P arena [q][key], 128B swz rows

    const int tid = threadIdx.x;
    const int w = tid >> 6, lane = tid & 63, lg = lane >> 4, q16 = lane & 15;
    // bijective XCD swizzle: 1024 wg = 8 xcd chunks of 128
    const int logical = ((blockIdx.x & 7) << 7) + (blockIdx.x >> 3);
    const int ks = logical & 7;
    const int qb = (logical >> 3) & 31;       // 32 q-blocks of 128
    const int b  = logical >> 8;
    const int q0 = (qb << 7) + (w << 5);      // wave's 32 q
    // blocked bases
    const ushort* qp = qg + (((size_t)b) << 18) + ((size_t)((qb << 2) + w) << 11);
    const ushort* kp = kg + (((size_t)b) << 18) + ((size_t)ks << 15);
    const ushort* vp = vg + (((size_t)b) << 18) + ((size_t)ks << 15);
    ushort* Pw = Ps[w];

    // hoist Q B-fragments (32 q x 64 c): contiguous lane-linear chunks
    bf16x8 aq[2][2];
#pragma unroll
    for (int qgi = 0; qgi < 2; ++qgi)
#pragma unroll
        for (int h = 0; h < 2; ++h)
            aq[qgi][h] = *(const bf16x8*)(qp + ((size_t)((((qgi << 1) + h) << 6) + lane) << 3));

    float l_[2] = {0.f, 0.f};
    f32x4 o_[4][2];                       // [ct][qgi]
#pragma unroll
    for (int ct = 0; ct < 4; ++ct)
#pragma unroll
        for (int qgi = 0; qgi < 2; ++qgi) o_[ct][qgi] = (f32x4){0.f, 0.f, 0.f, 0.f};

    // statically-named K register double buffer (no runtime indexing!)
    bf16x8 kfA[4][2], kfB[4][2];
    LOADK(kfA, 0);

#pragma unroll 1
    for (int kt2 = 0; kt2 < 8; kt2 += 2) {
        STEP(kfA, kfB, kt2, true);
        STEP(kfB, kfA, kt2 + 1, (kt2 + 1) < 7);
    }

    // deferred l reduction (once, not per tile)
#pragma unroll
    for (int qgi = 0; qgi < 2; ++qgi) {
        l_[qgi] += __shfl_xor(l_[qgi], 16);
        l_[qgi] += __shfl_xor(l_[qgi], 32);
    }

    // ---- store partial O~^T[c][n] (bf16) + l (f32) ----
    const size_t bs = (size_t)(b * NSPLIT + ks);
#pragma unroll
    for (int qgi = 0; qgi < 2; ++qgi) {
        const int n = q0 + (qgi << 4) + q16;
        ushort* ob = opart + ((bs * 64) << 12) + n;
#pragma unroll
        for (int ct = 0; ct < 4; ++ct)
#pragma unroll
            for (int r = 0; r < 4; ++r)
                ob[((size_t)((ct << 4) + (lg << 2) + r)) << 12] = f2bf(o_[ct][qgi][r]);
    }
    if (lg == 0) {
#pragma unroll
        for (int qgi = 0; qgi < 2; ++qgi) {
            const int n = q0 + (qgi << 4) + q16;
            lpart[bs * 4096 + n] = l_[qgi];
        }
    }
}

// ---------------------------------------------------------------------------
// Kernel 4: split-combine (plain sums) + output projection + bias + residual.
// Grid 256; NEW: XCD-AFFINITY decode matched to attn's writer swizzle —
// attn block (b, qb, ks) runs on XCD (2b + (qb>>4)), so combine block for
// (b, ntile) must run on XCD (2b + (ntile>>5)) to read opart from its own
// XCD's L2 (opart is written once, read once: all reads were cold misses).
// bid = idx*8 + xcd  ->  b = xcd>>1, ntile = (xcd&1)*32 + idx. Bijective.
// ---------------------------------------------------------------------------
__global__ __launch_bounds__(256) void combine_kernel(
    const ushort* __restrict__ opart, const float* __restrict__ lpart,
    const float* __restrict__ x, const float* __restrict__ Wp,
    const float* __restrict__ bp, float* __restrict__ out)
{
    __shared__ ushort Obf[64 * 64];    // combined O [n][c] bf16 swizzled
    __shared__ ushort Wps[64 * 64];    // Wp [oc][c] bf16 swizzled
    __shared__ float as_[64];          // 1/sum_l per n_local

    const int tid = threadIdx.x;
    const int w = tid >> 6, lane = tid & 63, g = lane >> 4, q16 = lane & 15;
    const int xcd = blockIdx.x & 7, idx = blockIdx.x >> 3;   // idx 0..31
    const int b = xcd >> 1;
    const int n0 = ((((xcd & 1) << 5) + idx) << 6);          // ntile*64

    {
        const int row = tid >> 2, cb = (tid & 3) << 4;
#pragma unroll
        for (int j = 0; j < 4; ++j) {
            float4 v = *(const float4*)(Wp + row * 64 + cb + j * 4);
            ushort4 h; h.x = f2bf(v.x); h.y = f2bf(v.y); h.z = f2bf(v.z); h.w = f2bf(v.w);
            *(ushort4*)((char*)Wps + swz(row, (cb + j * 4) * 2)) = h;
        }
    }
    if (tid < 64) {
        const int n = n0 + tid;
        float d = 0.f;
#pragma unroll
        for (int s = 0; s < NSPLIT; ++s)
            d += lpart[(size_t)(b * NSPLIT + s) * 4096 + n];
        as_[tid] = 1.0f / d;
    }
    __syncthreads();

    {
        const int c = tid >> 2, nb = (tid & 3) << 4;
        const ushort* base = opart + ((((size_t)(b * NSPLIT)) * 64 + c) << 12) + n0 + nb;
        const size_t sstride = (size_t)64 << 12;   // split stride in ushorts
        float acc[16];
#pragma unroll
        for (int e = 0; e < 16; ++e) acc[e] = 0.f;
#pragma unroll
        for (int s = 0; s < NSPLIT; ++s) {
            const ushort* p = base + s * sstride;
            uint4 d0 = *(const uint4*)(p);
            uint4 d1 = *(const uint4*)(p + 8);
            const uint uw[8] = {d0.x, d0.y, d0.z, d0.w, d1.x, d1.y, d1.z, d1.w};
#pragma unroll
            for (int j = 0; j < 8; ++j) {
                acc[2 * j]     += bf2f((ushort)(uw[j] & 0xffffu));
                acc[2 * j + 1] += bf2f((ushort)(uw[j] >> 16));
            }
        }
#pragma unroll
        for (int e = 0; e < 16; ++e) {
            int nl = nb + e;
            *(ushort*)((char*)Obf + swz(nl, c << 1)) = f2bf(acc[e] * as_[nl]);
        }
    }
    __syncthreads();

    {
        bf16x8 aw0 = ldfrag(Wps, (w << 4) + q16, (g << 4));
        bf16x8 aw1 = ldfrag(Wps, (w << 4) + q16, 64 + (g << 4));
        float bpv[4];
#pragma unroll
        for (int r = 0; r < 4; ++r) bpv[r] = bp[(w << 4) + (g << 2) + r];
#pragma unroll
        for (int qt = 0; qt < 4; ++qt) {
            f32x4 d = {0.f, 0.f, 0.f, 0.f};
            bf16x8 b0 = ldfrag(Obf, (qt << 4) + q16, (g << 4));
            bf16x8 b1 = ldfrag(Obf, (qt << 4) + q16, 64 + (g << 4));
            d = __builtin_amdgcn_mfma_f32_16x16x32_bf16(aw0, b0, d, 0, 0, 0);
            d = __builtin_amdgcn_mfma_f32_16x16x32_bf16(aw1, b1, d, 0, 0, 0);
#pragma unroll
            for (int r = 0; r < 4; ++r) {
                int oc = (w << 4) + (g << 2) + r;
                size_t addr = (((size_t)(b * CH + oc)) << 12) + n0 + (qt << 4) + q16;
                out[addr] = d[r] + bpv[r] + x[addr];
            }
        }
    }
}

// ---------------------------------------------------------------------------
extern "C" void kernel_launch(void* const* d_in, const int* in_sizes, int n_in,
                              void* d_out, int out_size, void* d_ws, size_t ws_size,
                              hipStream_t stream) {
    const float* x     = (const float*)d_in[0];
    const float* gamma = (const float*)d_in[1];
    const float* beta  = (const float*)d_in[2];
    const float* Wq    = (const float*)d_in[3];
    const float* bq    = (const float*)d_in[4];
    const float* Wk    = (const float*)d_in[5];
    const float* bk    = (const float*)d_in[6];
    const float* Wv    = (const float*)d_in[7];
    const float* bv    = (const float*)d_in[8];
    const float* Wp    = (const float*)d_in[9];
    const float* bp    = (const float*)d_in[10];
    float* out = (float*)d_out;

    float2* part = (float2*)d_ws;                      // 256 float2 = 2KB
    ushort* q_t = (ushort*)((char*)d_ws + 4096);       // blocked Q, 2MB
    ushort* k_t = q_t + (size_t)BATCH * NPOS * CH;     // blocked K, 2MB
    ushort* v_t = k_t + (size_t)BATCH * NPOS * CH;     // blocked V, 2MB
    ushort* opart = (ushort*)((char*)d_ws + 4096 + (size_t)3 * BATCH * NPOS * CH * 2);
    float* lpart = (float*)((char*)opart + (size_t)BATCH * NSPLIT * CH * NPOS * 2);

    hipLaunchKernelGGL(gn_part_kernel, dim3(256), dim3(256), 0, stream, x, part);
    hipLaunchKernelGGL(qkv_mfma_kernel, dim3(768), dim3(256), 0, stream,
                       x, part, gamma, beta, Wq, bq, Wk, bk, Wv, bv, q_t, k_t, v_t);
    hipLaunchKernelGGL(attn_mfma_kernel, dim3(1024), dim3(256), 0, stream,
                       q_t, k_t, v_t, opart, lpart);
    hipLaunchKernelGGL(combine_kernel, dim3(BATCH * 64), dim3(256), 0, stream,
                       opart, lpart, x, Wp, bp, out);
}

// Round 14
// 50.622 us; speedup vs baseline: 1.0843x; 1.0160x over previous
//
#include <hip/hip_runtime.h>
#include <hip/hip_bf16.h>
#include <math.h>

#define BATCH 4
#define CH    64
#define NPOS  4096   // 64*64
#define NGRP  8
#define CPG   8      // CH / NGRP
#define GEPS  1e-5f
#define NSPLIT 8     // K-dim split of attention
#define LOG2E 1.4426950408889634f

typedef __attribute__((ext_vector_type(8))) short bf16x8;   // 8 bf16 = 4 VGPRs
typedef __attribute__((ext_vector_type(4))) float f32x4;

// float -> bf16 bits (round-to-nearest-even)
__device__ __forceinline__ ushort f2bf(float f) {
    union { float f; uint32_t u; } v; v.f = f;
    uint32_t r = v.u + 0x7fffu + ((v.u >> 16) & 1u);
    return (ushort)(r >> 16);
}
__device__ __forceinline__ float bf2f(ushort u) {
    union { uint32_t u; float f; } v; v.u = ((uint32_t)u) << 16; return v.f;
}

// XOR swizzle within a 128B row: logical (row, byteInRow) -> physical byte offset
__device__ __forceinline__ uint32_t swz(uint32_t row, uint32_t byteInRow) {
    return (row << 7) + (byteInRow ^ ((row & 7u) << 4));
}

// 16B ds_read of an MFMA fragment slice
__device__ __forceinline__ bf16x8 ldfrag(const ushort* base, int row, int kbyte) {
    return *(const bf16x8*)((const char*)base + swz(row, kbyte));
}

// ---------------------------------------------------------------------------
// Kernel 1: GroupNorm partial sums. Grid 256: block = (bg, slice of 4096).
// ---------------------------------------------------------------------------
__global__ __launch_bounds__(256) void gn_part_kernel(const float* __restrict__ x,
                                                      float2* __restrict__ part) {
    const int blk = blockIdx.x;                      // bg*8 + slice
    const float4* xp4 = (const float4*)(x + (size_t)blk * 4096);
    float s1 = 0.f, s2 = 0.f;
    for (int i = threadIdx.x; i < 1024; i += 256) {
        float4 t = xp4[i];
        s1 += t.x + t.y + t.z + t.w;
        s2 += t.x * t.x + t.y * t.y + t.z * t.z + t.w * t.w;
    }
    __shared__ float sh1[256], sh2[256];
    const int tid = threadIdx.x;
    sh1[tid] = s1; sh2[tid] = s2;
    __syncthreads();
    for (int off = 128; off > 0; off >>= 1) {
        if (tid < off) { sh1[tid] += sh1[tid + off]; sh2[tid] += sh2[tid + off]; }
        __syncthreads();
    }
    if (tid == 0) { float2 r; r.x = sh1[0]; r.y = sh2[0]; part[blk] = r; }
}

// ---------------------------------------------------------------------------
// Kernel 2: fused GN-finish + GroupNorm-apply + ONE of {q,k,v} 1x1 conv.
// Grid 768. Outputs in FRAGMENT-BLOCKED layout (contiguous lane-linear 1KB
// chunks per MFMA fragment):
//   Q_blk[b][qgrp(128 of 32q)][qgi(2)][h(2)][lane(64)][8]
//   K_blk[b][kt(64)][nt(4)][h(2)][lane(64)][8]
//   V_blk[b][kt(64)][ct(4)][h(2)][lane(64)][8]
// q folds bias and 0.125*log2e (exp2-domain softmax).
// ---------------------------------------------------------------------------
__global__ __launch_bounds__(256) void qkv_mfma_kernel(
    const float* __restrict__ x, const float2* __restrict__ part,
    const float* __restrict__ gamma, const float* __restrict__ beta,
    const float* __restrict__ Wq, const float* __restrict__ bq,
    const float* __restrict__ Wk, const float* __restrict__ bk,
    const float* __restrict__ Wv, const float* __restrict__ bv,
    ushort* __restrict__ qg, ushort* __restrict__ kg, ushort* __restrict__ vg)
{
    __shared__ ushort xn[64 * 64];     // [n][c] swizzled bf16
    __shared__ ushort Wl[64 * 64];     // W [o][c] swizzled bf16
    __shared__ ushort ob[64 * 64];     // output bounce
    __shared__ float st[16];           // 8 groups * {mean, rstd} for this b

    const int tid = threadIdx.x;
    const int w = tid >> 6, lane = tid & 63, g = lane >> 4, q16 = lane & 15;
    const int m = blockIdx.x >> 8;               // 0=q 1=k 2=v
    const int bidx = blockIdx.x & 255;
    const int b = bidx >> 6, n0 = (bidx & 63) << 6;

    const float* W = (m == 0) ? Wq : (m == 1) ? Wk : Wv;

    {
        const int row = tid >> 2, cb = (tid & 3) << 4;
#pragma unroll
        for (int j = 0; j < 4; ++j) {
            float4 v = *(const float4*)(W + row * 64 + cb + j * 4);
            ushort4 h; h.x = f2bf(v.x); h.y = f2bf(v.y); h.z = f2bf(v.z); h.w = f2bf(v.w);
            *(ushort4*)((char*)Wl + swz(row, (cb + j * 4) * 2)) = h;
        }
    }
    if (tid < 64) {
        float2 p = part[b * 64 + tid];
        float s1 = p.x, s2 = p.y;
        s1 += __shfl_xor(s1, 1); s2 += __shfl_xor(s2, 1);
        s1 += __shfl_xor(s1, 2); s2 += __shfl_xor(s2, 2);
        s1 += __shfl_xor(s1, 4); s2 += __shfl_xor(s2, 4);
        if ((tid & 7) == 0) {
            const float inv = 1.0f / (float)(CPG * NPOS);
            float mean = s1 * inv;
            float var  = s2 * inv - mean * mean;
            st[(tid >> 3) * 2]     = mean;
            st[(tid >> 3) * 2 + 1] = rsqrtf(var + GEPS);
        }
    }
    __syncthreads();

    {
        const int c = tid >> 2, nb = (tid & 3) << 4;
        const float mean = st[(c >> 3) * 2];
        const float rstd = st[(c >> 3) * 2 + 1];
        const float gmm = gamma[c] * rstd;
        const float btt = beta[c] - mean * gmm;
        const float* xp = x + (((size_t)(b * CH + c)) << 12) + n0 + nb;
#pragma unroll
        for (int j = 0; j < 4; ++j) {
            float4 v = *(const float4*)(xp + j * 4);
            float vv[4] = {v.x, v.y, v.z, v.w};
#pragma unroll
            for (int e = 0; e < 4; ++e) {
                int n = nb + j * 4 + e;
                *(ushort*)((char*)xn + swz(n, c * 2)) = f2bf(vv[e] * gmm + btt);
            }
        }
    }
    __syncthreads();

    if (m < 2) {
        // ---- q/k: D[n][o] = xn[n][c] * W^T ----
        const float* bias = m ? bk : bq;
        const float scl = m ? 1.0f : 0.125f * LOG2E;   // q in exp2 domain
        bf16x8 ax0 = ldfrag(xn, (w << 4) + q16, (g << 4));
        bf16x8 ax1 = ldfrag(xn, (w << 4) + q16, 64 + (g << 4));
#pragma unroll
        for (int ot = 0; ot < 4; ++ot) {
            f32x4 acc = {0.f, 0.f, 0.f, 0.f};
            bf16x8 b0 = ldfrag(Wl, (ot << 4) + q16, (g << 4));
            bf16x8 b1 = ldfrag(Wl, (ot << 4) + q16, 64 + (g << 4));
            acc = __builtin_amdgcn_mfma_f32_16x16x32_bf16(ax0, b0, acc, 0, 0, 0);
            acc = __builtin_amdgcn_mfma_f32_16x16x32_bf16(ax1, b1, acc, 0, 0, 0);
            float bs = bias[(ot << 4) + q16];
#pragma unroll
            for (int r = 0; r < 4; ++r)
                *(ushort*)((char*)ob + swz((w << 4) + (g << 2) + r, ((ot << 4) + q16) << 1)) =
                    f2bf((acc[r] + bs) * scl);
        }
        __syncthreads();
        // ---- blocked store: ob[n][c] -> fragment chunks ----
        ushort* dst = (m ? kg : qg) + (((size_t)b) << 18);
#pragma unroll
        for (int i = 0; i < 2; ++i) {
            const int G = tid + (i << 8);            // 0..511
            const int lane_ = G & 63;
            const int h = (G >> 6) & 1;
            const int colb = (h << 5) + ((lane_ >> 4) << 3);   // ushorts
            if (m == 0) {
                const int qgi = (G >> 7) & 1;
                const int qgl = G >> 8;              // 0..1 (two 32-q groups)
                const int row = (qgl << 5) + (qgi << 4) + (lane_ & 15);
                int4 d = *(const int4*)((char*)ob + swz(row, colb << 1));
                *(int4*)(dst + (((size_t)(n0 >> 5) + qgl) << 11)
                             + ((size_t)((((qgi << 1) + h) << 6) + lane_) << 3)) = d;
            } else {
                const int nt = G >> 7;               // 0..3
                const int row = (nt << 4) + (lane_ & 15);
                int4 d = *(const int4*)((char*)ob + swz(row, colb << 1));
                *(int4*)(dst + ((size_t)(n0 >> 6) << 12)
                             + ((size_t)((((nt << 1) + h) << 6) + lane_) << 3)) = d;
            }
        }
    } else {
        // ---- v: D[o][n] = Wv * xn^T ----
        bf16x8 aw0 = ldfrag(Wl, (w << 4) + q16, (g << 4));
        bf16x8 aw1 = ldfrag(Wl, (w << 4) + q16, 64 + (g << 4));
#pragma unroll
        for (int nt = 0; nt < 4; ++nt) {
            f32x4 acc = {0.f, 0.f, 0.f, 0.f};
            bf16x8 b0 = ldfrag(xn, (nt << 4) + q16, (g << 4));
            bf16x8 b1 = ldfrag(xn, (nt << 4) + q16, 64 + (g << 4));
            acc = __builtin_amdgcn_mfma_f32_16x16x32_bf16(aw0, b0, acc, 0, 0, 0);
            acc = __builtin_amdgcn_mfma_f32_16x16x32_bf16(aw1, b1, acc, 0, 0, 0);
#pragma unroll
            for (int r = 0; r < 4; ++r) {
                float bs = bv[(w << 4) + (g << 2) + r];
                *(ushort*)((char*)ob + swz((w << 4) + (g << 2) + r, ((nt << 4) + q16) << 1)) =
                    f2bf(acc[r] + bs);
            }
        }
        __syncthreads();
        // ---- blocked store: ob[c][n_local] -> fragment chunks ----
        ushort* dst = vg + (((size_t)b) << 18) + ((size_t)(n0 >> 6) << 12);
#pragma unroll
        for (int i = 0; i < 2; ++i) {
            const int G = tid + (i << 8);            // 0..511
            const int lane_ = G & 63;
            const int h = (G >> 6) & 1;
            const int ct = G >> 7;                   // 0..3
            const int row = (ct << 4) + (lane_ & 15);        // channel
            const int colb = (h << 5) + ((lane_ >> 4) << 3); // key-local
            int4 d = *(const int4*)((char*)ob + swz(row, colb << 1));
            *(int4*)(dst + ((size_t)((((ct << 1) + h) << 6) + lane_) << 3)) = d;
        }
    }
}

// ---------------------------------------------------------------------------
// Kernel 3: attention, softmax-free (P = 2^s), K-split x8 — r11/r13 structure
// (proven best): 1024 blocks x 4 waves; 32 q/wave; blocked-layout direct-L2
// fragment loads; named K dbuf kfA/kfB; deferred l reduce.
// NEW: epilogue stores O~ in WAVE-BLOCKED lane-linear layout
//   opart[bs][qw(128)][ct*2+qgi(8)][lane(64)][4]
// -> 8 fully-coalesced b64 stores per wave (was 32 strided dword stores,
// 25% cacheline utilization).
// ---------------------------------------------------------------------------
#define LOADK(KF, KT)                                                          \
    _Pragma("unroll") for (int nt = 0; nt < 4; ++nt)                           \
    _Pragma("unroll") for (int h = 0; h < 2; ++h)                              \
        KF[nt][h] = *(const bf16x8*)(kp + (((size_t)(KT)) << 12) +             \
                     ((size_t)((((nt << 1) + h) << 6) + lane) << 3));

#define STEP(KF, KFN, KT, PREF)                                                \
  do {                                                                         \
    bf16x8 vf[4][2];                                                           \
    _Pragma("unroll") for (int ct = 0; ct < 4; ++ct)                           \
    _Pragma("unroll") for (int h = 0; h < 2; ++h)                              \
        vf[ct][h] = *(const bf16x8*)(vp + (((size_t)(KT)) << 12) +             \
                     ((size_t)((((ct << 1) + h) << 6) + lane) << 3));          \
    if (PREF) { LOADK(KFN, (KT) + 1); }                                        \
    f32x4 s_[4][2];                                                            \
    _Pragma("unroll") for (int nt = 0; nt < 4; ++nt)                           \
    _Pragma("unroll") for (int qgi = 0; qgi < 2; ++qgi) {                      \
        f32x4 z = {0.f, 0.f, 0.f, 0.f};                                        \
        z = __builtin_amdgcn_mfma_f32_16x16x32_bf16(KF[nt][0], aq[qgi][0], z, 0, 0, 0); \
        z = __builtin_amdgcn_mfma_f32_16x16x32_bf16(KF[nt][1], aq[qgi][1], z, 0, 0, 0); \
        s_[nt][qgi] = z;                                                       \
    }                                                                          \
    _Pragma("unroll") for (int qgi = 0; qgi < 2; ++qgi) {                      \
        _Pragma("unroll") for (int nt = 0; nt < 4; ++nt) {                     \
            float p0 = exp2f(s_[nt][qgi][0]);                                  \
            float p1 = exp2f(s_[nt][qgi][1]);                                  \
            float p2 = exp2f(s_[nt][qgi][2]);                                  \
            float p3 = exp2f(s_[nt][qgi][3]);                                  \
            l_[qgi] += (p0 + p1) + (p2 + p3);                                  \
            float2 t01; t01.x = p0; t01.y = p1;                                \
            float2 t23; t23.x = p2; t23.y = p3;                                \
            __hip_bfloat162 b01 = __float22bfloat162_rn(t01);                  \
            __hip_bfloat162 b23 = __float22bfloat162_rn(t23);                  \
            uint2 pk; pk.x = *(uint32_t*)&b01; pk.y = *(uint32_t*)&b23;        \
            *(uint2*)((char*)Pw + swz((qgi << 4) + q16, (nt << 5) + (lg << 3))) = pk; \
        }                                                                      \
    }                                                                          \
    asm volatile("" ::: "memory");                                             \
    bf16x8 pb[2][2];                                                           \
    _Pragma("unroll") for (int qgi = 0; qgi < 2; ++qgi) {                      \
        pb[qgi][0] = ldfrag(Pw, (qgi << 4) + q16, (lg << 4));                  \
        pb[qgi][1] = ldfrag(Pw, (qgi << 4) + q16, 64 + (lg << 4));             \
    }                                                                          \
    _Pragma("unroll") for (int ct = 0; ct < 4; ++ct)                           \
    _Pragma("unroll") for (int qgi = 0; qgi < 2; ++qgi) {                      \
        f32x4 o = o_[ct][qgi];                                                 \
        o = __builtin_amdgcn_mfma_f32_16x16x32_bf16(vf[ct][0], pb[qgi][0], o, 0, 0, 0); \
        o = __builtin_amdgcn_mfma_f32_16x16x32_bf16(vf[ct][1], pb[qgi][1], o, 0, 0, 0); \
        o_[ct][qgi] = o;                                                       \
    }                                                                          \
  } while (0)

__global__ __launch_bounds__(256) void attn_mfma_kernel(
    const ushort* __restrict__ qg, const ushort* __restrict__ kg,
    const ushort* __restrict__ vg,
    ushort* __restrict__ opart, float* __restrict__ lpart)
{
    __shared__ ushort Ps[4][32 * 64];   // per-wave P arena [q][key], 128B swz rows

    const int tid = threadIdx.x;
    const int w = tid >> 6, lane = tid & 63, lg = lane >> 4, q16 = lane & 15;
    // bijective XCD swizzle: 1024 wg = 8 xcd chunks of 128
    const int logical = ((blockIdx.x & 7) << 7) + (blockIdx.x >> 3);
    const int ks = logical & 7;
    const int qb = (logical >> 3) & 31;       // 32 q-blocks of 128
    const int b  = logical >> 8;
    const int q0 = (qb << 7) + (w << 5);      // wave's 32 q
    // blocked bases
    const ushort* qp = qg + (((size_t)b) << 18) + ((size_t)((qb << 2) + w) << 11);
    const ushort* kp = kg + (((size_t)b) << 18) + ((size_t)ks << 15);
    const ushort* vp = vg + (((size_t)b) << 18) + ((size_t)ks << 15);
    ushort* Pw = Ps[w];

    // hoist Q B-fragments (32 q x 64 c): contiguous lane-linear chunks
    bf16x8 aq[2][2];
#pragma unroll
    for (int qgi = 0; qgi < 2; ++qgi)
#pragma unroll
        for (int h = 0; h < 2; ++h)
            aq[qgi][h] = *(const bf16x8*)(qp + ((size_t)((((qgi << 1) + h) << 6) + lane) << 3));

    float l_[2] = {0.f, 0.f};
    f32x4 o_[4][2];                       // [ct][qgi]
#pragma unroll
    for (int ct = 0; ct < 4; ++ct)
#pragma unroll
        for (int qgi = 0; qgi < 2; ++qgi) o_[ct][qgi] = (f32x4){0.f, 0.f, 0.f, 0.f};

    // statically-named K register double buffer (no runtime indexing!)
    bf16x8 kfA[4][2], kfB[4][2];
    LOADK(kfA, 0);

#pragma unroll 1
    for (int kt2 = 0; kt2 < 8; kt2 += 2) {
        STEP(kfA, kfB, kt2, true);
        STEP(kfB, kfA, kt2 + 1, (kt2 + 1) < 7);
    }

    // deferred l reduction (once, not per tile)
#pragma unroll
    for (int qgi = 0; qgi < 2; ++qgi) {
        l_[qgi] += __shfl_xor(l_[qgi], 16);
        l_[qgi] += __shfl_xor(l_[qgi], 32);
    }

    // ---- store O~ wave-blocked: opart[bs][qw][ct*2+qgi][lane][4] ----
    const size_t bs = (size_t)(b * NSPLIT + ks);
    const int qw = (qb << 2) + w;
    ushort* ob = opart + (((bs << 7) + qw) << 11);   // 2048 ushorts per (bs,qw)
#pragma unroll
    for (int ct = 0; ct < 4; ++ct)
#pragma unroll
        for (int qgi = 0; qgi < 2; ++qgi) {
            ushort4 h;
            h.x = f2bf(o_[ct][qgi][0]);
            h.y = f2bf(o_[ct][qgi][1]);
            h.z = f2bf(o_[ct][qgi][2]);
            h.w = f2bf(o_[ct][qgi][3]);
            *(ushort4*)(ob + (((((ct << 1) + qgi) << 6) + lane) << 2)) = h;
        }
    if (lg == 0) {
#pragma unroll
        for (int qgi = 0; qgi < 2; ++qgi) {
            const int n = q0 + (qgi << 4) + q16;
            lpart[bs * 4096 + n] = l_[qgi];
        }
    }
}

// ---------------------------------------------------------------------------
// Kernel 4: split-combine (plain sums) + output projection + bias + residual.
// Grid 256; XCD-affinity decode matched to attn's writer swizzle (r13 win).
// NEW: reads opart in the wave-blocked layout — warp w mirrors attn's ct=w;
// 32 fully-coalesced 512B/warp uint2 loads per warp.
// ---------------------------------------------------------------------------
__global__ __launch_bounds__(256) void combine_kernel(
    const ushort* __restrict__ opart, const float* __restrict__ lpart,
    const float* __restrict__ x, const float* __restrict__ Wp,
    const float* __restrict__ bp, float* __restrict__ out)
{
    __shared__ ushort Obf[64 * 64];    // combined O [n][c] bf16 swizzled
    __shared__ ushort Wps[64 * 64];    // Wp [oc][c] bf16 swizzled
    __shared__ float as_[64];          // 1/sum_l per n_local

    const int tid = threadIdx.x;
    const int w = tid >> 6, lane = tid & 63, lg = lane >> 4, q16 = lane & 15;
    const int g = lg;
    const int xcd = blockIdx.x & 7, idx = blockIdx.x >> 3;   // idx 0..31
    const int b = xcd >> 1;
    const int n0 = ((((xcd & 1) << 5) + idx) << 6);          // ntile*64

    {
        const int row = tid >> 2, cb = (tid & 3) << 4;
#pragma unroll
        for (int j = 0; j < 4; ++j) {
            float4 v = *(const float4*)(Wp + row * 64 + cb + j * 4);
            ushort4 h; h.x = f2bf(v.x); h.y = f2bf(v.y); h.z = f2bf(v.z); h.w = f2bf(v.w);
            *(ushort4*)((char*)Wps + swz(row, (cb + j * 4) * 2)) = h;
        }
    }
    if (tid < 64) {
        const int n = n0 + tid;
        float d = 0.f;
#pragma unroll
        for (int s = 0; s < NSPLIT; ++s)
            d += lpart[(size_t)(b * NSPLIT + s) * 4096 + n];
        as_[tid] = 1.0f / d;
    }
    __syncthreads();

    // ---- accumulate splits from wave-blocked opart; warp w owns ct=w ----
    {
        const int qw0 = n0 >> 5;          // two 32-q groups per 64-n tile
        float acc[2][2][4];
#pragma unroll
        for (int qwi = 0; qwi < 2; ++qwi)
#pragma unroll
            for (int qgi = 0; qgi < 2; ++qgi)
#pragma unroll
                for (int r = 0; r < 4; ++r) acc[qwi][qgi][r] = 0.f;
#pragma unroll
        for (int s = 0; s < NSPLIT; ++s) {
            const size_t bs = (size_t)(b * NSPLIT + s);
#pragma unroll
            for (int qwi = 0; qwi < 2; ++qwi)
#pragma unroll
                for (int qgi = 0; qgi < 2; ++qgi) {
                    uint2 d = *(const uint2*)(opart + (((bs << 7) + qw0 + qwi) << 11)
                                              + (((((w << 1) + qgi) << 6) + lane) << 2));
                    acc[qwi][qgi][0] += bf2f((ushort)(d.x & 0xffffu));
                    acc[qwi][qgi][1] += bf2f((ushort)(d.x >> 16));
                    acc[qwi][qgi][2] += bf2f((ushort)(d.y & 0xffffu));
                    acc[qwi][qgi][3] += bf2f((ushort)(d.y >> 16));
                }
        }
        // write into Obf[n][c] swizzled: c = w*16 + lg*4 + r
        const int c0b = ((w << 4) + (lg << 2)) << 1;   // byte offset of c0
#pragma unroll
        for (int qwi = 0; qwi < 2; ++qwi)
#pragma unroll
            for (int qgi = 0; qgi < 2; ++qgi) {
                const int nl = (qwi << 5) + (qgi << 4) + q16;
                const float a = as_[nl];
                ushort4 h;
                h.x = f2bf(acc[qwi][qgi][0] * a);
                h.y = f2bf(acc[qwi][qgi][1] * a);
                h.z = f2bf(acc[qwi][qgi][2] * a);
                h.w = f2bf(acc[qwi][qgi][3] * a);
                *(ushort4*)((char*)Obf + swz(nl, c0b)) = h;
            }
    }
    __syncthreads();

    {
        bf16x8 aw0 = ldfrag(Wps, (w << 4) + q16, (g << 4));
        bf16x8 aw1 = ldfrag(Wps, (w << 4) + q16, 64 + (g << 4));
        float bpv[4];
#pragma unroll
        for (int r = 0; r < 4; ++r) bpv[r] = bp[(w << 4) + (g << 2) + r];
#pragma unroll
        for (int qt = 0; qt < 4; ++qt) {
            f32x4 d = {0.f, 0.f, 0.f, 0.f};
            bf16x8 b0 = ldfrag(Obf, (qt << 4) + q16, (g << 4));
            bf16x8 b1 = ldfrag(Obf, (qt << 4) + q16, 64 + (g << 4));
            d = __builtin_amdgcn_mfma_f32_16x16x32_bf16(aw0, b0, d, 0, 0, 0);
            d = __builtin_amdgcn_mfma_f32_16x16x32_bf16(aw1, b1, d, 0, 0, 0);
#pragma unroll
            for (int r = 0; r < 4; ++r) {
                int oc = (w << 4) + (g << 2) + r;
                size_t addr = (((size_t)(b * CH + oc)) << 12) + n0 + (qt << 4) + q16;
                out[addr] = d[r] + bpv[r] + x[addr];
            }
        }
    }
}

// ---------------------------------------------------------------------------
extern "C" void kernel_launch(void* const* d_in, const int* in_sizes, int n_in,
                              void* d_out, int out_size, void* d_ws, size_t ws_size,
                              hipStream_t stream) {
    const float* x     = (const float*)d_in[0];
    const float* gamma = (const float*)d_in[1];
    const float* beta  = (const float*)d_in[2];
    const float* Wq    = (const float*)d_in[3];
    const float* bq    = (const float*)d_in[4];
    const float* Wk    = (const float*)d_in[5];
    const float* bk    = (const float*)d_in[6];
    const float* Wv    = (const float*)d_in[7];
    const float* bv    = (const float*)d_in[8];
    const float* Wp    = (const float*)d_in[9];
    const float* bp    = (const float*)d_in[10];
    float* out = (float*)d_out;

    float2* part = (float2*)d_ws;                      // 256 float2 = 2KB
    ushort* q_t = (ushort*)((char*)d_ws + 4096);       // blocked Q, 2MB
    ushort* k_t = q_t + (size_t)BATCH * NPOS * CH;     // blocked K, 2MB
    ushort* v_t = k_t + (size_t)BATCH * NPOS * CH;     // blocked V, 2MB
    ushort* opart = (ushort*)((char*)d_ws + 4096 + (size_t)3 * BATCH * NPOS * CH * 2);
    float* lpart = (float*)((char*)opart + (size_t)BATCH * NSPLIT * CH * NPOS * 2);

    hipLaunchKernelGGL(gn_part_kernel, dim3(256), dim3(256), 0, stream, x, part);
    hipLaunchKernelGGL(qkv_mfma_kernel, dim3(768), dim3(256), 0, stream,
                       x, part, gamma, beta, Wq, bq, Wk, bk, Wv, bv, q_t, k_t, v_t);
    hipLaunchKernelGGL(attn_mfma_kernel, dim3(1024), dim3(256), 0, stream,
                       q_t, k_t, v_t, opart, lpart);
    hipLaunchKernelGGL(combine_kernel, dim3(BATCH * 64), dim3(256), 0, stream,
                       opart, lpart, x, Wp, bp, out);
}